// Round 3
// baseline (726.215 us; speedup 1.0000x reference)
//
#include <hip/hip_runtime.h>
#include <math.h>

#define TWO_PI 6.28318530717958647692f

// ws float offsets
#define OFF_XO    0u
#define OFF_S1    4194304u
#define OFF_XF    5242880u
#define OFF_G     5505024u
#define OFF_T     5767168u
#define OFF_WT    7864320u
#define OFF_TW1   12058624u
#define OFF_TW2   12062720u
#define OFF_CK    12079104u
#define OFF_CM    12087296u
#define OFF_H2    12095488u   // now bf16 (short): 2 branches x 4,194,304 shorts
#define OFF_WP    16289792u   // w1p/w2p packed bf16 weights (2 x 32768 shorts)
#define OFF_SS    20484096u
#define OFF_CS    20500480u
#define OFF_COLQ  20500736u
#define OFF_COLH2 20502784u   // 512 cols x 5 stats (h2, h2^2, z*h2, z, z^2)
#define OFF_COLA  20505344u
#define OFF_GN1   20507392u
#define OFF_ALPHA 20507648u
#define OFF_BETA  20508160u
#define OFF_GN3   20508672u
#define ZERO_CNT  21248u   // SS..COLH2 contiguous

typedef short bfrag __attribute__((ext_vector_type(8)));
typedef short short4v __attribute__((ext_vector_type(4)));
typedef float f32x4 __attribute__((ext_vector_type(4)));

__device__ __forceinline__ short f2bs(float f) {
  union { float f; unsigned u; } v; v.f = f;
  unsigned r = (v.u + 0x7fffu + ((v.u >> 16) & 1u)) >> 16;
  return (short)r;
}
__device__ __forceinline__ float bs2f(short s) {
  union { unsigned u; float f; } v; v.u = ((unsigned)(unsigned short)s) << 16;
  return v.f;
}

// ---------------- twiddle LUT fill ----------------
__global__ __launch_bounds__(256)
void k_twfill(float* __restrict__ lut) {
  int idx = blockIdx.x * 256 + threadIdx.x;
  const float step = TWO_PI / 128.0f;
  if (idx < 4096) {                       // TW1t[v][2k+p]
    int v = idx >> 5, j = idx & 31, k = j >> 1, p = j & 1;
    float s, c; sincosf(step * (float)((k * v) & 127), &s, &c);
    lut[idx] = p ? -s : c;
  } else if (idx < 20480) {               // TW2t[2u+pp][2mi+p]
    int li = idx - 4096; int q = li >> 6, j3 = li & 63;
    int u = q >> 1, pp = q & 1, mi = j3 >> 1, p = j3 & 1;
    int m = mi < 16 ? mi : mi + 96;
    float s, c; sincosf(step * (float)((m * u) & 127), &s, &c);
    lut[idx] = pp == 0 ? (p == 0 ? c : -s) : (p == 0 ? s : c);
  } else if (idx < 28672) {               // CKt[2k+pp][2v+p]
    int li = idx - 20480; int j4 = li >> 8, r5 = li & 255;
    int k = j4 >> 1, pp = j4 & 1, v = r5 >> 1, p = r5 & 1;
    float ck = k ? 2.f : 1.f;
    float s, c; sincosf(step * (float)((k * v) & 127), &s, &c);
    lut[idx] = pp == 0 ? (p == 0 ? ck * c : ck * s) : (p == 0 ? -ck * s : ck * c);
  } else if (idx < 36864) {               // CMt[2mi+p][u]  (scale folded)
    int li = idx - 28672; int j5 = li >> 7, u = li & 127;
    int mi = j5 >> 1, p = j5 & 1; int m = mi < 16 ? mi : mi + 96;
    float s, c; sincosf(step * (float)((m * u) & 127), &s, &c);
    lut[idx] = (p == 0 ? c : -s) * (1.0f / 16384.0f);
  }
}

// ---------------- weight transpose: wt[mi][k][i][o][2] ----------------
__global__ __launch_bounds__(256)
void k_wtrans(const float* __restrict__ fw1, const float* __restrict__ fw2,
              float* __restrict__ wt) {
  int bid = blockIdx.x, t = threadIdx.x;
  int mi = bid >> 4, ic = bid & 15;
  int i = ic * 4 + (t >> 6), o = t & 63;
  int xs = mi & 15;
  const float* src = (mi < 16 ? fw1 : fw2) + (size_t)(((i * 64 + o) * 16 + xs) * 16) * 2;
  float4 r[8];
  #pragma unroll
  for (int j = 0; j < 8; ++j) r[j] = ((const float4*)src)[j];
  float2* dst = (float2*)wt;
  #pragma unroll
  for (int j = 0; j < 8; ++j) {
    int k0 = 2 * j;
    dst[((size_t)(mi * 16 + k0) * 64 + i) * 64 + o]     = make_float2(r[j].x, r[j].y);
    dst[((size_t)(mi * 16 + k0 + 1) * 64 + i) * 64 + o] = make_float2(r[j].z, r[j].w);
  }
}

// ---------------- FFN weight pack (bf16 fragment layout) ----------------
__global__ __launch_bounds__(256)
void k_wprep(const float* __restrict__ bW1, const float* __restrict__ fW1,
             const float* __restrict__ bW2, const float* __restrict__ fW2,
             short* __restrict__ w1p, short* __restrict__ w2p) {
  int idx = blockIdx.x * 256 + threadIdx.x;      // 65536 total
  if (idx < 32768) {                             // w1p[br][rt16][ks2][l64][j8]
    int br = idx >> 14, rem = idx & 16383;
    int rt = rem >> 10, ks = (rem >> 9) & 1;
    int l = (rem >> 3) & 63, j = rem & 7;
    const float* W = br ? fW1 : bW1;
    int kk = 32 * ks + (l >> 4) * 8 + j;
    int n = 16 * rt + (l & 15);
    w1p[idx] = f2bs(W[kk * 256 + n]);
  } else {                                       // w2p[br][ct4][ks8][l64][j8]
    int i2 = idx - 32768;
    int br = i2 >> 14, rem = i2 & 16383;
    int ct = rem >> 12, ks = (rem >> 9) & 7;
    int l = (rem >> 3) & 63, j = rem & 7;
    const float* W = br ? fW2 : bW2;
    int kk = 32 * ks + (l >> 4) * 8 + j;
    int n = 16 * ct + (l & 15);
    w2p[i2] = f2bs(W[kk * 64 + n]);
  }
}

// ---------------- fft1 ----------------
__global__ __launch_bounds__(256)
void k_fft1(const float* __restrict__ x, const float* __restrict__ z,
            const float* __restrict__ TW1t, float* __restrict__ S1) {
  __shared__ float diff[128 * 64];
  int t = threadIdx.x, bid = blockIdx.x;
  int b = bid >> 7, u = bid & 127;
  size_t bx = ((size_t)b * 16384 + (size_t)u * 128) * 64;
  size_t bz = ((size_t)b * 32768 + (size_t)u * 128) * 64;
  #pragma unroll
  for (int j = 0; j < 32; ++j) { int idx = t + 256 * j; diff[idx] = x[bx + idx] - z[bz + idx]; }
  __syncthreads();
  int kk = t >> 4, i0 = (t & 15) * 4;
  float r0[4] = {}, r1[4] = {};
  #pragma unroll 4
  for (int v = 0; v < 128; ++v) {
    float2 tw = *(const float2*)&TW1t[v * 32 + kk * 2];
    float4 d = *(const float4*)&diff[v * 64 + i0];
    float dv[4] = {d.x, d.y, d.z, d.w};
    #pragma unroll
    for (int q = 0; q < 4; ++q) { r0[q] += tw.x * dv[q]; r1[q] += tw.y * dv[q]; }
  }
  size_t o0 = ((size_t)b * 256 + 2 * u) * 1024 + kk * 64 + i0;
  *(float4*)&S1[o0]        = make_float4(r0[0], r0[1], r0[2], r0[3]);
  *(float4*)&S1[o0 + 1024] = make_float4(r1[0], r1[1], r1[2], r1[3]);
}

// ---------------- fft2 ----------------
__global__ __launch_bounds__(256)
void k_fft2(const float* __restrict__ S1, const float* __restrict__ TW2t,
            float* __restrict__ XF) {
  __shared__ float Bs[256 * 32];
  int t = threadIdx.x, bid = blockIdx.x;
  int b = bid >> 5, ch = bid & 31;
  size_t sbase = (size_t)b * 262144 + ch * 32;
  #pragma unroll
  for (int j = 0; j < 32; ++j) {
    int idx = t + 256 * j; int q = idx >> 5, c = idx & 31;
    Bs[idx] = S1[sbase + (size_t)q * 1024 + c];
  }
  __syncthreads();
  int r0 = (t >> 4) * 4, c0 = (t & 15) * 2;
  float acc[4][2] = {};
  #pragma unroll 4
  for (int q = 0; q < 256; ++q) {
    float4 a = *(const float4*)&TW2t[q * 64 + r0];
    float2 bb = *(const float2*)&Bs[q * 32 + c0];
    float av[4] = {a.x, a.y, a.z, a.w};
    #pragma unroll
    for (int i = 0; i < 4; ++i) { acc[i][0] += av[i] * bb.x; acc[i][1] += av[i] * bb.y; }
  }
  #pragma unroll
  for (int i = 0; i < 4; ++i)
    *(float2*)&XF[(size_t)b * 65536 + (size_t)(r0 + i) * 1024 + ch * 32 + c0] =
        make_float2(acc[i][0], acc[i][1]);
}

// ---------------- einsum ----------------
__global__ __launch_bounds__(256)
void k_einsum(const float* __restrict__ XF, const float* __restrict__ wt,
              float* __restrict__ G) {
  __shared__ float xin[4][2][64];
  int t = threadIdx.x, bid = blockIdx.x;
  int mi = bid >> 4, k = bid & 15;
  #pragma unroll
  for (int rep = 0; rep < 2; ++rep) {
    int f = rep * 256 + t; int bb = f >> 7, rem = f & 127, p = rem >> 6, i = rem & 63;
    xin[bb][p][i] = XF[(size_t)bb * 65536 + (size_t)(2 * mi + p) * 1024 + k * 64 + i];
  }
  __syncthreads();
  int b = t >> 6, o = t & 63;
  float gr = 0.f, gi = 0.f;
  const float2* w2 = (const float2*)wt + (size_t)(mi * 16 + k) * 4096 + o;
  #pragma unroll 8
  for (int i = 0; i < 64; ++i) {
    float2 w = w2[(size_t)i * 64];
    float xr = xin[b][0][i], xi = xin[b][1][i];
    gr += xr * w.x - xi * w.y;
    gi += xr * w.y + xi * w.x;
  }
  size_t gb = ((size_t)(b * 32 + mi) * 32 + 2 * k) * 64 + o;
  G[gb] = gr; G[gb + 64] = gi;
}

// ---------------- inv1 ----------------
__global__ __launch_bounds__(256)
void k_inv1(const float* __restrict__ G, const float* __restrict__ CKt,
            float* __restrict__ T) {
  __shared__ float GG[32 * 64];
  int t = threadIdx.x, bid = blockIdx.x;
  int b = bid >> 7, mi = (bid >> 2) & 31, vq = bid & 3;
  size_t gbase = (size_t)(b * 32 + mi) * 2048;
  #pragma unroll
  for (int j = 0; j < 8; ++j) GG[t + 256 * j] = G[gbase + t + 256 * j];
  __syncthreads();
  int r0 = (t >> 4) * 4, o0 = (t & 15) * 4;
  float acc[4][4] = {};
  #pragma unroll 4
  for (int j4 = 0; j4 < 32; ++j4) {
    float4 a = *(const float4*)&CKt[j4 * 256 + vq * 64 + r0];
    float4 bb = *(const float4*)&GG[j4 * 64 + o0];
    float av[4] = {a.x, a.y, a.z, a.w}, bv[4] = {bb.x, bb.y, bb.z, bb.w};
    #pragma unroll
    for (int i = 0; i < 4; ++i)
      #pragma unroll
      for (int j = 0; j < 4; ++j) acc[i][j] += av[i] * bv[j];
  }
  #pragma unroll
  for (int ii = 0; ii < 4; ++ii) {
    int r = vq * 64 + r0 + ii; int v = r >> 1, p = r & 1;
    *(float4*)&T[((size_t)(b * 128 + v) * 64 + 2 * mi + p) * 64 + o0] =
        make_float4(acc[ii][0], acc[ii][1], acc[ii][2], acc[ii][3]);
  }
}

// ---------------- inv2 ----------------
__global__ __launch_bounds__(256)
void k_inv2(const float* __restrict__ T, const float* __restrict__ CMt,
            float* __restrict__ xo) {
  __shared__ float Ts[64 * 64];
  int t = threadIdx.x, bid = blockIdx.x;
  int b = bid >> 8, v = (bid >> 1) & 127, uh = bid & 1;
  size_t tb = (size_t)(b * 128 + v) * 4096;
  #pragma unroll
  for (int j = 0; j < 16; ++j) Ts[t + 256 * j] = T[tb + t + 256 * j];
  __syncthreads();
  int u0 = uh * 64 + (t >> 4) * 4, o0 = (t & 15) * 4;
  float acc[4][4] = {};
  #pragma unroll 4
  for (int j5 = 0; j5 < 64; ++j5) {
    float4 a = *(const float4*)&CMt[j5 * 128 + u0];
    float4 bb = *(const float4*)&Ts[j5 * 64 + o0];
    float av[4] = {a.x, a.y, a.z, a.w}, bv[4] = {bb.x, bb.y, bb.z, bb.w};
    #pragma unroll
    for (int i = 0; i < 4; ++i)
      #pragma unroll
      for (int j = 0; j < 4; ++j) acc[i][j] += av[i] * bv[j];
  }
  #pragma unroll
  for (int ii = 0; ii < 4; ++ii)
    *(float4*)&xo[(size_t)b * 1048576 + (size_t)(u0 + ii) * 8192 + v * 64 + o0] =
        make_float4(acc[ii][0], acc[ii][1], acc[ii][2], acc[ii][3]);
}

// ---------------- xo stats: SS[b]=X^T X, CS[b]=col sums ----------------
__global__ __launch_bounds__(256)
void k_xostats(const float* __restrict__ xo, float* __restrict__ SS,
               float* __restrict__ CS) {
  __shared__ float Xs[128 * 64];
  int t = threadIdx.x, bid = blockIdx.x;
  int b = bid >> 7, rc = bid & 127;
  size_t base = (size_t)b * 1048576 + (size_t)rc * 8192;
  #pragma unroll
  for (int j = 0; j < 32; ++j) Xs[t + 256 * j] = xo[base + t + 256 * j];
  __syncthreads();
  int c1 = (t >> 4) * 4, c2 = (t & 15) * 4;
  float acc[4][4] = {};
  #pragma unroll 2
  for (int r = 0; r < 128; ++r) {
    float4 a = *(const float4*)&Xs[r * 64 + c1];
    float4 bb = *(const float4*)&Xs[r * 64 + c2];
    float av[4] = {a.x, a.y, a.z, a.w}, bv[4] = {bb.x, bb.y, bb.z, bb.w};
    #pragma unroll
    for (int i = 0; i < 4; ++i)
      #pragma unroll
      for (int j = 0; j < 4; ++j) acc[i][j] += av[i] * bv[j];
  }
  float* ssb = SS + b * 4096;
  #pragma unroll
  for (int i = 0; i < 4; ++i)
    #pragma unroll
    for (int j = 0; j < 4; ++j) atomicAdd(&ssb[(c1 + i) * 64 + c2 + j], acc[i][j]);
  if (t < 64) {
    float s = 0.f;
    for (int r = 0; r < 128; ++r) s += Xs[r * 64 + t];
    atomicAdd(&CS[b * 64 + t], s);
  }
}

// ---------------- per-col quadratic form ----------------
__global__ __launch_bounds__(256)
void k_colq(const float* __restrict__ bW1, const float* __restrict__ fW1,
            const float* __restrict__ SS, const float* __restrict__ CS,
            float* __restrict__ colq, float* __restrict__ cola) {
  int bid = blockIdx.x, t = threadIdx.x;
  int br = bid >> 5, b = (bid >> 3) & 3, jc = bid & 7;
  const float* W1 = br ? fW1 : bW1;
  float w[64];
  #pragma unroll
  for (int l = 0; l < 64; ++l) w[l] = W1[l * 256 + t];
  const float* ssb = SS + b * 4096;
  float q = 0.f;
  for (int jj = 0; jj < 8; ++jj) {
    int j = jc * 8 + jj;
    float sj = 0.f;
    #pragma unroll
    for (int l = 0; l < 64; ++l) sj += ssb[j * 64 + l] * w[l];
    q += W1[j * 256 + t] * sj;
  }
  atomicAdd(&colq[(br * 4 + b) * 256 + t], q);
  if (jc == 0) {
    float a = 0.f;
    #pragma unroll
    for (int l = 0; l < 64; ++l) a += CS[b * 64 + l] * w[l];
    cola[(br * 4 + b) * 256 + t] = a;
  }
}

// ---------------- gn1 group stats (analytic) ----------------
__global__ __launch_bounds__(256)
void k_gstats(const float* __restrict__ colq, const float* __restrict__ cola,
              const float* __restrict__ bb1, const float* __restrict__ fb1,
              float* __restrict__ gn1) {
  int t = threadIdx.x; if (t >= 128) return;
  int br = t >> 6, bg = t & 63, b = bg >> 4, g = bg & 15;
  const float* b1 = br ? fb1 : bb1;
  const float invR = 1.0f / 16384.0f;
  float se = 0.f, sq = 0.f;
  for (int ci = 0; ci < 16; ++ci) {
    int c = g * 16 + ci;
    float A = cola[(br * 4 + b) * 256 + c];
    float Q = colq[(br * 4 + b) * 256 + c];
    float bc = b1[c];
    se += A * invR + bc;
    sq += (Q + 2.f * bc * A) * invR + bc * bc;
  }
  float mean = se * 0.0625f;
  float var = sq * 0.0625f - mean * mean;
  gn1[((br * 4 + b) * 16 + g) * 2] = mean;
  gn1[((br * 4 + b) * 16 + g) * 2 + 1] = rsqrtf(var + 1e-5f);
}

// ---------------- fused MFMA FFN ----------------
// GEMM1 (transposed): C1T = W1^T x xo^T -> GN1+ReLU -> hact (LDS bf16, row-major)
// GEMM2: h2 = hact x W2 -> bias -> write h2 (bf16), accumulate col stats incl z
__global__ __launch_bounds__(256)
void k_ffn(const float* __restrict__ xo, const short* __restrict__ w1p,
           const short* __restrict__ w2p,
           const float* __restrict__ b1, const float* __restrict__ g1w,
           const float* __restrict__ g1b, const float* __restrict__ gn1b,
           const float* __restrict__ b2, const float* __restrict__ z, int br,
           short* __restrict__ h2, float* __restrict__ colh2) {
  __shared__ short hact[4][16][264];     // per wave: 16 rows x (256+8 pad) bf16
  int t = threadIdx.x;
  int w = t >> 6, l = t & 63, q = l >> 4, lm = l & 15;
  int rows0 = blockIdx.x * 64;
  int b = rows0 >> 14;

  // B-frags for GEMM1: xo rows (this wave's stripe), k = q*8+j (+32*ks)
  const float* xp = xo + (size_t)(rows0 + 16 * w + lm) * 64 + q * 8;
  bfrag bx0, bx1;
  {
    float4 a0 = *(const float4*)(xp);
    float4 a1 = *(const float4*)(xp + 4);
    float4 a2 = *(const float4*)(xp + 32);
    float4 a3 = *(const float4*)(xp + 36);
    float v0[8] = {a0.x, a0.y, a0.z, a0.w, a1.x, a1.y, a1.z, a1.w};
    float v1[8] = {a2.x, a2.y, a2.z, a2.w, a3.x, a3.y, a3.z, a3.w};
    #pragma unroll
    for (int j = 0; j < 8; ++j) { bx0[j] = f2bs(v0[j]); bx1[j] = f2bs(v1[j]); }
  }
  const bfrag* w1f = (const bfrag*)(w1p + (size_t)br * 16384);
  const bfrag* w2f = (const bfrag*)(w2p + (size_t)br * 16384);

  // GEMM1 + fused GN1/ReLU epilogue, one 16x16 output tile (h-cols) at a time
  #pragma unroll 4
  for (int rt = 0; rt < 16; ++rt) {
    f32x4 c = {0.f, 0.f, 0.f, 0.f};
    c = __builtin_amdgcn_mfma_f32_16x16x32_bf16(w1f[(rt * 2 + 0) * 64 + l], bx0, c, 0, 0, 0);
    c = __builtin_amdgcn_mfma_f32_16x16x32_bf16(w1f[(rt * 2 + 1) * 64 + l], bx1, c, 0, 0, 0);
    int c1b = 16 * rt + 4 * q;           // group g == rt
    float4 l1 = *(const float4*)&b1[c1b];
    float4 gw = *(const float4*)&g1w[c1b];
    float4 gb = *(const float4*)&g1b[c1b];
    float gm = gn1b[(b * 16 + rt) * 2];
    float gr = gn1b[(b * 16 + rt) * 2 + 1];
    short4v sv;
    sv[0] = f2bs(fmaxf((c[0] + l1.x - gm) * gr * gw.x + gb.x, 0.f));
    sv[1] = f2bs(fmaxf((c[1] + l1.y - gm) * gr * gw.y + gb.y, 0.f));
    sv[2] = f2bs(fmaxf((c[2] + l1.z - gm) * gr * gw.z + gb.z, 0.f));
    sv[3] = f2bs(fmaxf((c[3] + l1.w - gm) * gr * gw.w + gb.w, 0.f));
    *(short4v*)&hact[w][lm][c1b] = sv;   // ds_write_b64, contiguous cols
  }

  // GEMM2: A-frags from hact (same-wave data only -> no barrier)
  f32x4 acc2[4];
  #pragma unroll
  for (int ct = 0; ct < 4; ++ct) acc2[ct] = (f32x4){0.f, 0.f, 0.f, 0.f};
  #pragma unroll
  for (int ks = 0; ks < 8; ++ks) {
    bfrag af = *(const bfrag*)&hact[w][lm][32 * ks + 8 * q];   // ds_read_b128
    #pragma unroll
    for (int ct = 0; ct < 4; ++ct)
      acc2[ct] = __builtin_amdgcn_mfma_f32_16x16x32_bf16(af, w2f[(ct * 8 + ks) * 64 + l],
                                                         acc2[ct], 0, 0, 0);
  }

  // epilogue: bias, write h2 bf16, col stats (h2, h2^2, z*h2, z, z^2)
  size_t zrowbase = (size_t)(b * 2 + br) * 16384 + (size_t)(rows0 & 16383) + 16 * w;
  #pragma unroll
  for (int ct = 0; ct < 4; ++ct) {
    float b2v = b2[16 * ct + lm];
    float sv = 0.f, sq = 0.f, szh = 0.f, sz = 0.f, szq = 0.f;
    #pragma unroll
    for (int rr = 0; rr < 4; ++rr) {
      int row = 4 * q + rr;
      float v = acc2[ct][rr] + b2v;
      float zv = z[(zrowbase + row) * 64 + 16 * ct + lm];
      h2[(size_t)(rows0 + 16 * w + row) * 64 + 16 * ct + lm] = f2bs(v);
      sv += v; sq += v * v; szh += zv * v; sz += zv; szq += zv * zv;
    }
    sv += __shfl_xor(sv, 16);  sv += __shfl_xor(sv, 32);
    sq += __shfl_xor(sq, 16);  sq += __shfl_xor(sq, 32);
    szh += __shfl_xor(szh, 16); szh += __shfl_xor(szh, 32);
    sz += __shfl_xor(sz, 16);  sz += __shfl_xor(sz, 32);
    szq += __shfl_xor(szq, 16); szq += __shfl_xor(szq, 32);
    if (l < 16) {
      float* ch = colh2 + (size_t)((br * 4 + b) * 64 + 16 * ct + lm) * 5;
      atomicAdd(ch + 0, sv);
      atomicAdd(ch + 1, sq);
      atomicAdd(ch + 2, szh);
      atomicAdd(ch + 3, sz);
      atomicAdd(ch + 4, szq);
    }
  }
}

// ---------------- final stats: gn2 (exact) + gn3 (analytic) ----------------
__global__ __launch_bounds__(256)
void k_fstats(const float* __restrict__ colh2,
              const float* __restrict__ bg2w, const float* __restrict__ bg2b,
              const float* __restrict__ fg2w, const float* __restrict__ fg2b,
              float* __restrict__ alpha, float* __restrict__ beta,
              float* __restrict__ gn3) {
  __shared__ float m2r2[32][2];
  __shared__ float ab[2][4][64][2];
  int t = threadIdx.x;
  const float invR = 1.0f / 16384.0f;
  if (t < 32) {
    int br = t >> 4, b = (t >> 2) & 3, g = t & 3;
    float se = 0.f, sq = 0.f;
    for (int ci = 0; ci < 16; ++ci) {
      const float* ch = colh2 + (size_t)((br * 4 + b) * 64 + g * 16 + ci) * 5;
      se += ch[0]; sq += ch[1];
    }
    float mean = se * invR * 0.0625f;
    float Eq = sq * invR * 0.0625f;
    m2r2[t][0] = mean;
    m2r2[t][1] = rsqrtf(Eq - mean * mean + 1e-5f);
  }
  __syncthreads();
  #pragma unroll
  for (int rep = 0; rep < 2; ++rep) {
    int idx = t + rep * 256;
    int br = idx >> 8, b = (idx >> 6) & 3, c = idx & 63, g = c >> 4;
    const float* g2w = br ? fg2w : bg2w;
    const float* g2b = br ? fg2b : bg2b;
    float m2 = m2r2[(br * 4 + b) * 4 + g][0];
    float r2 = m2r2[(br * 4 + b) * 4 + g][1];
    float a = r2 * g2w[c];
    float bt = g2b[c] - m2 * a;
    ab[br][b][c][0] = a; ab[br][b][c][1] = bt;
    alpha[(br * 4 + b) * 64 + c] = a;
    beta[(br * 4 + b) * 64 + c] = bt;
  }
  __syncthreads();
  if (t < 32) {
    int br = t >> 4, b = (t >> 2) & 3, g = t & 3;
    float se = 0.f, sq = 0.f;
    for (int ci = 0; ci < 16; ++ci) {
      int c = g * 16 + ci;
      const float* ch = colh2 + (size_t)((br * 4 + b) * 64 + c) * 5;
      float Eh = ch[0] * invR, Eh2 = ch[1] * invR, Ezh = ch[2] * invR;
      float Ez = ch[3] * invR, Ez2 = ch[4] * invR;
      float a = ab[br][b][c][0], bt = ab[br][b][c][1];
      se += Ez + a * Eh + bt;
      sq += Ez2 + a * a * Eh2 + bt * bt + 2.f * a * Ezh + 2.f * bt * Ez + 2.f * a * bt * Eh;
    }
    float m3 = se * 0.0625f;
    float var = sq * 0.0625f - m3 * m3;
    gn3[t * 2] = m3;
    gn3[t * 2 + 1] = rsqrtf(var + 1e-5f);
  }
}

// ---------------- h3 + norm3 fused single pass ----------------
__global__ __launch_bounds__(256)
void k_h3final(const short* __restrict__ h2, const float* __restrict__ z,
               const float* __restrict__ alpha, const float* __restrict__ beta,
               const float* __restrict__ gn3, const float* __restrict__ g3w,
               const float* __restrict__ g3b, int br, float* __restrict__ out) {
  int t = threadIdx.x, bid = blockIdx.x;
  int b = bid >> 8, rc = bid & 255;
  int col = t & 63, rq = t >> 6;
  int g = col >> 4;
  float a = alpha[(br * 4 + b) * 64 + col];
  float bt = beta[(br * 4 + b) * 64 + col];
  float m3 = gn3[((br * 4 + b) * 4 + g) * 2];
  float r3 = gn3[((br * 4 + b) * 4 + g) * 2 + 1];
  float A2 = r3 * g3w[col];
  float B2 = g3b[col] - m3 * A2;
  size_t hbase = (size_t)b * 1048576 + (size_t)rc * 4096;
  size_t zbase = (size_t)(b * 2 + br) * 1048576 + (size_t)rc * 4096;
  for (int j = 0; j < 16; ++j) {
    size_t off = (size_t)(rq + 4 * j) * 64 + col;
    float h3 = z[zbase + off] + a * bs2f(h2[hbase + off]) + bt;
    out[zbase + off] = h3 * A2 + B2;
  }
}

extern "C" void kernel_launch(void* const* d_in, const int* in_sizes, int n_in,
                              void* d_out, int out_size, void* d_ws, size_t ws_size,
                              hipStream_t stream) {
  const float* z   = (const float*)d_in[0];
  const float* x   = (const float*)d_in[1];
  const float* fw1 = (const float*)d_in[2];
  const float* fw2 = (const float*)d_in[3];
  const float* P[20];
  for (int i = 0; i < 20; ++i) P[i] = (const float*)d_in[4 + i];
  // P[0..9] = b_{l1w,l1b,l2w,l2b,g1w,g1b,g2w,g2b,g3w,g3b}; P[10..19] = f_{...}

  float* ws = (float*)d_ws;
  float* xo   = ws + OFF_XO;
  float* S1   = ws + OFF_S1;
  float* XF   = ws + OFF_XF;
  float* G    = ws + OFF_G;
  float* T    = ws + OFF_T;
  float* wt   = ws + OFF_WT;
  float* TW1t = ws + OFF_TW1;
  float* TW2t = ws + OFF_TW2;
  float* CKt  = ws + OFF_CK;
  float* CMt  = ws + OFF_CM;
  short* h2s  = (short*)(ws + OFF_H2);
  short* w1p  = (short*)(ws + OFF_WP);
  short* w2p  = w1p + 32768;
  float* SS   = ws + OFF_SS;
  float* CS   = ws + OFF_CS;
  float* colq = ws + OFF_COLQ;
  float* colh2= ws + OFF_COLH2;
  float* cola = ws + OFF_COLA;
  float* gn1  = ws + OFF_GN1;
  float* alph = ws + OFF_ALPHA;
  float* beta = ws + OFF_BETA;
  float* gn3  = ws + OFF_GN3;
  float* out  = (float*)d_out;

  hipMemsetAsync(SS, 0, ZERO_CNT * sizeof(float), stream);
  k_twfill<<<144, 256, 0, stream>>>(TW1t);
  k_wtrans<<<512, 256, 0, stream>>>(fw1, fw2, wt);
  k_wprep<<<256, 256, 0, stream>>>(P[0], P[10], P[2], P[12], w1p, w2p);
  k_fft1<<<512, 256, 0, stream>>>(x, z, TW1t, S1);
  k_fft2<<<128, 256, 0, stream>>>(S1, TW2t, XF);
  k_einsum<<<512, 256, 0, stream>>>(XF, wt, G);
  k_inv1<<<512, 256, 0, stream>>>(G, CKt, T);
  k_inv2<<<1024, 256, 0, stream>>>(T, CMt, xo);
  k_xostats<<<512, 256, 0, stream>>>(xo, SS, CS);
  k_colq<<<64, 256, 0, stream>>>(P[0], P[10], SS, CS, colq, cola);
  k_gstats<<<1, 256, 0, stream>>>(colq, cola, P[1], P[11], gn1);
  for (int br = 0; br < 2; ++br) {
    const float* const* q = P + br * 10;
    k_ffn<<<1024, 256, 0, stream>>>(xo, w1p, w2p, q[1], q[4], q[5], gn1 + br * 128,
                                    q[3], z, br, h2s + (size_t)br * 4194304, colh2);
  }
  k_fstats<<<1, 256, 0, stream>>>(colh2, P[6], P[7], P[16], P[17], alph, beta, gn3);
  for (int br = 0; br < 2; ++br) {
    const float* const* q = P + br * 10;
    k_h3final<<<1024, 256, 0, stream>>>(h2s + (size_t)br * 4194304, z, alph, beta, gn3,
                                        q[8], q[9], br, out);
  }
}

// Round 5
// 321.143 us; speedup vs baseline: 2.2613x; 2.2613x over previous
//
#include <hip/hip_runtime.h>
#include <math.h>

#define TWO_PI 6.28318530717958647692f

// ws float offsets
#define OFF_XO    0u
#define OFF_S1    4194304u   // aliased: cpart (2 x 327680) after fft2 consumed
#define OFF_XF    5242880u
#define OFF_G     5505024u
#define OFF_T     5767168u   // aliased: SSpart (512 x 4096) after inv2 consumed
#define OFF_WT    7864320u
#define OFF_TW1   12058624u
#define OFF_TW2   12062720u
#define OFF_CK    12079104u
#define OFF_CM    12087296u
#define OFF_H2    12095488u  // f32 h2: 2 branches x 4,194,304 floats
#define OFF_WP    20484096u  // w1p/w2p packed bf16 (65536 shorts = 32768 floats)
#define OFF_CSP   20516864u  // CSpart 512 x 64
#define OFF_SS    20549632u  // 4 x 4096
#define OFF_CS    20566016u  // 4 x 64
#define OFF_CQP   20566272u  // colqpart 2 x 4 x 8 x 256
#define OFF_COLA  20582656u  // 2 x 4 x 256
#define OFF_GN1   20584704u  // 256
#define OFF_COLH2 20584960u  // 2 x 4 x 64 x 5
#define OFF_ALPHA 20587520u
#define OFF_BETA  20588032u
#define OFF_GN3   20588544u

typedef short bfrag __attribute__((ext_vector_type(8)));
typedef float f32x4 __attribute__((ext_vector_type(4)));

__device__ __forceinline__ short f2bs(float f) {
  union { float f; unsigned u; } v; v.f = f;
  unsigned r = (v.u + 0x7fffu + ((v.u >> 16) & 1u)) >> 16;
  return (short)r;
}

// ---------------- twiddle LUT fill ----------------
__global__ __launch_bounds__(256)
void k_twfill(float* __restrict__ lut) {
  int idx = blockIdx.x * 256 + threadIdx.x;
  const float step = TWO_PI / 128.0f;
  if (idx < 4096) {                       // TW1t[v][2k+p]
    int v = idx >> 5, j = idx & 31, k = j >> 1, p = j & 1;
    float s, c; sincosf(step * (float)((k * v) & 127), &s, &c);
    lut[idx] = p ? -s : c;
  } else if (idx < 20480) {               // TW2t[2u+pp][2mi+p]
    int li = idx - 4096; int q = li >> 6, j3 = li & 63;
    int u = q >> 1, pp = q & 1, mi = j3 >> 1, p = j3 & 1;
    int m = mi < 16 ? mi : mi + 96;
    float s, c; sincosf(step * (float)((m * u) & 127), &s, &c);
    lut[idx] = pp == 0 ? (p == 0 ? c : -s) : (p == 0 ? s : c);
  } else if (idx < 28672) {               // CKt[2k+pp][2v+p]
    int li = idx - 20480; int j4 = li >> 8, r5 = li & 255;
    int k = j4 >> 1, pp = j4 & 1, v = r5 >> 1, p = r5 & 1;
    float ck = k ? 2.f : 1.f;
    float s, c; sincosf(step * (float)((k * v) & 127), &s, &c);
    lut[idx] = pp == 0 ? (p == 0 ? ck * c : ck * s) : (p == 0 ? -ck * s : ck * c);
  } else if (idx < 36864) {               // CMt[2mi+p][u]  (scale folded)
    int li = idx - 28672; int j5 = li >> 7, u = li & 127;
    int mi = j5 >> 1, p = j5 & 1; int m = mi < 16 ? mi : mi + 96;
    float s, c; sincosf(step * (float)((m * u) & 127), &s, &c);
    lut[idx] = (p == 0 ? c : -s) * (1.0f / 16384.0f);
  }
}

// ---------------- weight transpose: wt[mi][k][i][o][2] ----------------
__global__ __launch_bounds__(256)
void k_wtrans(const float* __restrict__ fw1, const float* __restrict__ fw2,
              float* __restrict__ wt) {
  int bid = blockIdx.x, t = threadIdx.x;
  int mi = bid >> 4, ic = bid & 15;
  int i = ic * 4 + (t >> 6), o = t & 63;
  int xs = mi & 15;
  const float* src = (mi < 16 ? fw1 : fw2) + (size_t)(((i * 64 + o) * 16 + xs) * 16) * 2;
  float4 r[8];
  #pragma unroll
  for (int j = 0; j < 8; ++j) r[j] = ((const float4*)src)[j];
  float2* dst = (float2*)wt;
  #pragma unroll
  for (int j = 0; j < 8; ++j) {
    int k0 = 2 * j;
    dst[((size_t)(mi * 16 + k0) * 64 + i) * 64 + o]     = make_float2(r[j].x, r[j].y);
    dst[((size_t)(mi * 16 + k0 + 1) * 64 + i) * 64 + o] = make_float2(r[j].z, r[j].w);
  }
}

// ---------------- FFN weight pack (bf16 fragment layout) ----------------
__global__ __launch_bounds__(256)
void k_wprep(const float* __restrict__ bW1, const float* __restrict__ fW1,
             const float* __restrict__ bW2, const float* __restrict__ fW2,
             short* __restrict__ w1p, short* __restrict__ w2p) {
  int idx = blockIdx.x * 256 + threadIdx.x;      // 65536 total
  if (idx < 32768) {                             // w1p[br][rt16][ks2][l64][j8]
    int br = idx >> 14, rem = idx & 16383;
    int rt = rem >> 10, ks = (rem >> 9) & 1;
    int l = (rem >> 3) & 63, j = rem & 7;
    const float* W = br ? fW1 : bW1;
    int kk = 32 * ks + (l >> 4) * 8 + j;
    int n = 16 * rt + (l & 15);
    w1p[idx] = f2bs(W[kk * 256 + n]);
  } else {                                       // w2p[br][ct4][ks8][l64][j8]
    int i2 = idx - 32768;
    int br = i2 >> 14, rem = i2 & 16383;
    int ct = rem >> 12, ks = (rem >> 9) & 7;
    int l = (rem >> 3) & 63, j = rem & 7;
    const float* W = br ? fW2 : bW2;
    int kk = 32 * ks + (l >> 4) * 8 + j;
    int n = 16 * ct + (l & 15);
    w2p[i2] = f2bs(W[kk * 64 + n]);
  }
}

// ---------------- fft1 ----------------
__global__ __launch_bounds__(256)
void k_fft1(const float* __restrict__ x, const float* __restrict__ z,
            const float* __restrict__ TW1t, float* __restrict__ S1) {
  __shared__ float diff[128 * 64];
  int t = threadIdx.x, bid = blockIdx.x;
  int b = bid >> 7, u = bid & 127;
  size_t bx = ((size_t)b * 16384 + (size_t)u * 128) * 64;
  size_t bz = ((size_t)b * 32768 + (size_t)u * 128) * 64;
  #pragma unroll
  for (int j = 0; j < 32; ++j) { int idx = t + 256 * j; diff[idx] = x[bx + idx] - z[bz + idx]; }
  __syncthreads();
  int kk = t >> 4, i0 = (t & 15) * 4;
  float r0[4] = {}, r1[4] = {};
  #pragma unroll 4
  for (int v = 0; v < 128; ++v) {
    float2 tw = *(const float2*)&TW1t[v * 32 + kk * 2];
    float4 d = *(const float4*)&diff[v * 64 + i0];
    float dv[4] = {d.x, d.y, d.z, d.w};
    #pragma unroll
    for (int q = 0; q < 4; ++q) { r0[q] += tw.x * dv[q]; r1[q] += tw.y * dv[q]; }
  }
  size_t o0 = ((size_t)b * 256 + 2 * u) * 1024 + kk * 64 + i0;
  *(float4*)&S1[o0]        = make_float4(r0[0], r0[1], r0[2], r0[3]);
  *(float4*)&S1[o0 + 1024] = make_float4(r1[0], r1[1], r1[2], r1[3]);
}

// ---------------- fft2 ----------------
__global__ __launch_bounds__(256)
void k_fft2(const float* __restrict__ S1, const float* __restrict__ TW2t,
            float* __restrict__ XF) {
  __shared__ float Bs[256 * 32];
  int t = threadIdx.x, bid = blockIdx.x;
  int b = bid >> 5, ch = bid & 31;
  size_t sbase = (size_t)b * 262144 + ch * 32;
  #pragma unroll
  for (int j = 0; j < 32; ++j) {
    int idx = t + 256 * j; int q = idx >> 5, c = idx & 31;
    Bs[idx] = S1[sbase + (size_t)q * 1024 + c];
  }
  __syncthreads();
  int r0 = (t >> 4) * 4, c0 = (t & 15) * 2;
  float acc[4][2] = {};
  #pragma unroll 4
  for (int q = 0; q < 256; ++q) {
    float4 a = *(const float4*)&TW2t[q * 64 + r0];
    float2 bb = *(const float2*)&Bs[q * 32 + c0];
    float av[4] = {a.x, a.y, a.z, a.w};
    #pragma unroll
    for (int i = 0; i < 4; ++i) { acc[i][0] += av[i] * bb.x; acc[i][1] += av[i] * bb.y; }
  }
  #pragma unroll
  for (int i = 0; i < 4; ++i)
    *(float2*)&XF[(size_t)b * 65536 + (size_t)(r0 + i) * 1024 + ch * 32 + c0] =
        make_float2(acc[i][0], acc[i][1]);
}

// ---------------- einsum ----------------
__global__ __launch_bounds__(256)
void k_einsum(const float* __restrict__ XF, const float* __restrict__ wt,
              float* __restrict__ G) {
  __shared__ float xin[4][2][64];
  int t = threadIdx.x, bid = blockIdx.x;
  int mi = bid >> 4, k = bid & 15;
  #pragma unroll
  for (int rep = 0; rep < 2; ++rep) {
    int f = rep * 256 + t; int bb = f >> 7, rem = f & 127, p = rem >> 6, i = rem & 63;
    xin[bb][p][i] = XF[(size_t)bb * 65536 + (size_t)(2 * mi + p) * 1024 + k * 64 + i];
  }
  __syncthreads();
  int b = t >> 6, o = t & 63;
  float gr = 0.f, gi = 0.f;
  const float2* w2 = (const float2*)wt + (size_t)(mi * 16 + k) * 4096 + o;
  #pragma unroll 8
  for (int i = 0; i < 64; ++i) {
    float2 w = w2[(size_t)i * 64];
    float xr = xin[b][0][i], xi = xin[b][1][i];
    gr += xr * w.x - xi * w.y;
    gi += xr * w.y + xi * w.x;
  }
  size_t gb = ((size_t)(b * 32 + mi) * 32 + 2 * k) * 64 + o;
  G[gb] = gr; G[gb + 64] = gi;
}

// ---------------- inv1 ----------------
__global__ __launch_bounds__(256)
void k_inv1(const float* __restrict__ G, const float* __restrict__ CKt,
            float* __restrict__ T) {
  __shared__ float GG[32 * 64];
  int t = threadIdx.x, bid = blockIdx.x;
  int b = bid >> 7, mi = (bid >> 2) & 31, vq = bid & 3;
  size_t gbase = (size_t)(b * 32 + mi) * 2048;
  #pragma unroll
  for (int j = 0; j < 8; ++j) GG[t + 256 * j] = G[gbase + t + 256 * j];
  __syncthreads();
  int r0 = (t >> 4) * 4, o0 = (t & 15) * 4;
  float acc[4][4] = {};
  #pragma unroll 4
  for (int j4 = 0; j4 < 32; ++j4) {
    float4 a = *(const float4*)&CKt[j4 * 256 + vq * 64 + r0];
    float4 bb = *(const float4*)&GG[j4 * 64 + o0];
    float av[4] = {a.x, a.y, a.z, a.w}, bv[4] = {bb.x, bb.y, bb.z, bb.w};
    #pragma unroll
    for (int i = 0; i < 4; ++i)
      #pragma unroll
      for (int j = 0; j < 4; ++j) acc[i][j] += av[i] * bv[j];
  }
  #pragma unroll
  for (int ii = 0; ii < 4; ++ii) {
    int r = vq * 64 + r0 + ii; int v = r >> 1, p = r & 1;
    *(float4*)&T[((size_t)(b * 128 + v) * 64 + 2 * mi + p) * 64 + o0] =
        make_float4(acc[ii][0], acc[ii][1], acc[ii][2], acc[ii][3]);
  }
}

// ---------------- inv2 ----------------
__global__ __launch_bounds__(256)
void k_inv2(const float* __restrict__ T, const float* __restrict__ CMt,
            float* __restrict__ xo) {
  __shared__ float Ts[64 * 64];
  int t = threadIdx.x, bid = blockIdx.x;
  int b = bid >> 8, v = (bid >> 1) & 127, uh = bid & 1;
  size_t tb = (size_t)(b * 128 + v) * 4096;
  #pragma unroll
  for (int j = 0; j < 16; ++j) Ts[t + 256 * j] = T[tb + t + 256 * j];
  __syncthreads();
  int u0 = uh * 64 + (t >> 4) * 4, o0 = (t & 15) * 4;
  float acc[4][4] = {};
  #pragma unroll 4
  for (int j5 = 0; j5 < 64; ++j5) {
    float4 a = *(const float4*)&CMt[j5 * 128 + u0];
    float4 bb = *(const float4*)&Ts[j5 * 64 + o0];
    float av[4] = {a.x, a.y, a.z, a.w}, bv[4] = {bb.x, bb.y, bb.z, bb.w};
    #pragma unroll
    for (int i = 0; i < 4; ++i)
      #pragma unroll
      for (int j = 0; j < 4; ++j) acc[i][j] += av[i] * bv[j];
  }
  #pragma unroll
  for (int ii = 0; ii < 4; ++ii)
    *(float4*)&xo[(size_t)b * 1048576 + (size_t)(u0 + ii) * 8192 + v * 64 + o0] =
        make_float4(acc[ii][0], acc[ii][1], acc[ii][2], acc[ii][3]);
}

// ---------------- xo stats partials: SSpart[bid]=X^T X (128 rows), CSpart ----------------
__global__ __launch_bounds__(256)
void k_xostats(const float* __restrict__ xo, float* __restrict__ SSpart,
               float* __restrict__ CSpart) {
  __shared__ float Xs[128 * 64];
  int t = threadIdx.x, bid = blockIdx.x;
  size_t base = (size_t)bid * 8192;
  #pragma unroll
  for (int j = 0; j < 32; ++j) Xs[t + 256 * j] = xo[base + t + 256 * j];
  __syncthreads();
  int c1 = (t >> 4) * 4, c2 = (t & 15) * 4;
  float acc[4][4] = {};
  #pragma unroll 2
  for (int r = 0; r < 128; ++r) {
    float4 a = *(const float4*)&Xs[r * 64 + c1];
    float4 bb = *(const float4*)&Xs[r * 64 + c2];
    float av[4] = {a.x, a.y, a.z, a.w}, bv[4] = {bb.x, bb.y, bb.z, bb.w};
    #pragma unroll
    for (int i = 0; i < 4; ++i)
      #pragma unroll
      for (int j = 0; j < 4; ++j) acc[i][j] += av[i] * bv[j];
  }
  float* ssb = SSpart + (size_t)bid * 4096;
  #pragma unroll
  for (int i = 0; i < 4; ++i)
    #pragma unroll
    for (int j = 0; j < 4; ++j) ssb[(c1 + i) * 64 + c2 + j] = acc[i][j];
  if (t < 64) {
    float s = 0.f;
    for (int r = 0; r < 128; ++r) s += Xs[r * 64 + t];
    CSpart[(size_t)bid * 64 + t] = s;
  }
}

// ---------------- reduce SSpart/CSpart ----------------
__global__ __launch_bounds__(256)
void k_ssred(const float* __restrict__ SSpart, const float* __restrict__ CSpart,
             float* __restrict__ SS, float* __restrict__ CS) {
  int bid = blockIdx.x, t = threadIdx.x;
  if (bid < 64) {
    int idx = bid * 256 + t;
    int b = idx >> 12, e = idx & 4095;
    float s = 0.f;
    for (int rc = 0; rc < 128; ++rc) s += SSpart[(size_t)(b * 128 + rc) * 4096 + e];
    SS[idx] = s;
  } else {
    int b = t >> 6, c = t & 63;
    float s = 0.f;
    for (int rc = 0; rc < 128; ++rc) s += CSpart[(size_t)(b * 128 + rc) * 64 + c];
    CS[t] = s;
  }
}

// ---------------- per-col quadratic form partials ----------------
__global__ __launch_bounds__(256)
void k_colq(const float* __restrict__ bW1, const float* __restrict__ fW1,
            const float* __restrict__ SS, const float* __restrict__ CS,
            float* __restrict__ colqpart, float* __restrict__ cola) {
  int bid = blockIdx.x, t = threadIdx.x;
  int br = bid >> 5, b = (bid >> 3) & 3, jc = bid & 7;
  const float* W1 = br ? fW1 : bW1;
  float w[64];
  #pragma unroll
  for (int l = 0; l < 64; ++l) w[l] = W1[l * 256 + t];
  const float* ssb = SS + b * 4096;
  float q = 0.f;
  for (int jj = 0; jj < 8; ++jj) {
    int j = jc * 8 + jj;
    float sj = 0.f;
    #pragma unroll
    for (int l = 0; l < 64; ++l) sj += ssb[j * 64 + l] * w[l];
    q += W1[j * 256 + t] * sj;
  }
  colqpart[(size_t)bid * 256 + t] = q;
  if (jc == 0) {
    float a = 0.f;
    #pragma unroll
    for (int l = 0; l < 64; ++l) a += CS[b * 64 + l] * w[l];
    cola[(br * 4 + b) * 256 + t] = a;
  }
}

// ---------------- gn1 group stats (analytic) ----------------
__global__ __launch_bounds__(256)
void k_gstats(const float* __restrict__ colqpart, const float* __restrict__ cola,
              const float* __restrict__ bb1, const float* __restrict__ fb1,
              float* __restrict__ gn1) {
  int t = threadIdx.x; if (t >= 128) return;
  int br = t >> 6, bg = t & 63, b = bg >> 4, g = bg & 15;
  const float* b1 = br ? fb1 : bb1;
  const float invR = 1.0f / 16384.0f;
  float se = 0.f, sq = 0.f;
  for (int ci = 0; ci < 16; ++ci) {
    int c = g * 16 + ci;
    float A = cola[(br * 4 + b) * 256 + c];
    float Q = 0.f;
    #pragma unroll
    for (int jc = 0; jc < 8; ++jc)
      Q += colqpart[(size_t)((br * 4 + b) * 8 + jc) * 256 + c];
    float bc = b1[c];
    se += A * invR + bc;
    sq += (Q + 2.f * bc * A) * invR + bc * bc;
  }
  float mean = se * 0.0625f;
  float var = sq * 0.0625f - mean * mean;
  gn1[((br * 4 + b) * 16 + g) * 2] = mean;
  gn1[((br * 4 + b) * 16 + g) * 2 + 1] = rsqrtf(var + 1e-5f);
}

// ---------------- fused MFMA FFN (no atomics; block partials) ----------------
__global__ __launch_bounds__(256)
void k_ffn(const float* __restrict__ xo, const short* __restrict__ w1p,
           const short* __restrict__ w2p,
           const float* __restrict__ b1, const float* __restrict__ g1w,
           const float* __restrict__ g1b, const float* __restrict__ gn1b,
           const float* __restrict__ b2, const float* __restrict__ z, int br,
           float* __restrict__ h2, float* __restrict__ cpart) {
  __shared__ short hact[4][16][264];     // per wave: 16 rows x (256+8 pad) bf16
  __shared__ float red[4][320];
  int t = threadIdx.x;
  int w = t >> 6, l = t & 63, q = l >> 4, lm = l & 15;
  int rows0 = blockIdx.x * 64;
  int b = rows0 >> 14;

  // B-frags for GEMM1: xo rows (this wave's stripe), k = q*8+j (+32*ks)
  const float* xp = xo + (size_t)(rows0 + 16 * w + lm) * 64 + q * 8;
  bfrag bx0, bx1;
  {
    float4 a0 = *(const float4*)(xp);
    float4 a1 = *(const float4*)(xp + 4);
    float4 a2 = *(const float4*)(xp + 32);
    float4 a3 = *(const float4*)(xp + 36);
    float v0[8] = {a0.x, a0.y, a0.z, a0.w, a1.x, a1.y, a1.z, a1.w};
    float v1[8] = {a2.x, a2.y, a2.z, a2.w, a3.x, a3.y, a3.z, a3.w};
    #pragma unroll
    for (int j = 0; j < 8; ++j) { bx0[j] = f2bs(v0[j]); bx1[j] = f2bs(v1[j]); }
  }
  const bfrag* w1f = (const bfrag*)(w1p + (size_t)br * 16384);
  const bfrag* w2f = (const bfrag*)(w2p + (size_t)br * 16384);

  // GEMM1 + fused GN1/ReLU epilogue
  #pragma unroll 4
  for (int rt = 0; rt < 16; ++rt) {
    f32x4 c = {0.f, 0.f, 0.f, 0.f};
    c = __builtin_amdgcn_mfma_f32_16x16x32_bf16(w1f[(rt * 2 + 0) * 64 + l], bx0, c, 0, 0, 0);
    c = __builtin_amdgcn_mfma_f32_16x16x32_bf16(w1f[(rt * 2 + 1) * 64 + l], bx1, c, 0, 0, 0);
    int c1b = 16 * rt + 4 * q;           // group g == rt
    float4 l1 = *(const float4*)&b1[c1b];
    float4 gw = *(const float4*)&g1w[c1b];
    float4 gb = *(const float4*)&g1b[c1b];
    float gm = gn1b[(b * 16 + rt) * 2];
    float gr = gn1b[(b * 16 + rt) * 2 + 1];
    hact[w][lm][c1b + 0] = f2bs(fmaxf((c[0] + l1.x - gm) * gr * gw.x + gb.x, 0.f));
    hact[w][lm][c1b + 1] = f2bs(fmaxf((c[1] + l1.y - gm) * gr * gw.y + gb.y, 0.f));
    hact[w][lm][c1b + 2] = f2bs(fmaxf((c[2] + l1.z - gm) * gr * gw.z + gb.z, 0.f));
    hact[w][lm][c1b + 3] = f2bs(fmaxf((c[3] + l1.w - gm) * gr * gw.w + gb.w, 0.f));
  }

  // GEMM2 (same-wave LDS only -> no barrier needed before reads)
  f32x4 acc2[4];
  #pragma unroll
  for (int ct = 0; ct < 4; ++ct) acc2[ct] = (f32x4){0.f, 0.f, 0.f, 0.f};
  #pragma unroll
  for (int ks = 0; ks < 8; ++ks) {
    bfrag af = *(const bfrag*)&hact[w][lm][32 * ks + 8 * q];
    #pragma unroll
    for (int ct = 0; ct < 4; ++ct)
      acc2[ct] = __builtin_amdgcn_mfma_f32_16x16x32_bf16(af, w2f[(ct * 8 + ks) * 64 + l],
                                                         acc2[ct], 0, 0, 0);
  }

  // epilogue: bias, write h2 (f32), per-wave stats -> LDS -> block partial
  size_t zrowbase = (size_t)(b * 2 + br) * 16384 + (size_t)(rows0 & 16383) + 16 * w;
  #pragma unroll
  for (int ct = 0; ct < 4; ++ct) {
    float b2v = b2[16 * ct + lm];
    float sv = 0.f, sq = 0.f, szh = 0.f, sz = 0.f, szq = 0.f;
    #pragma unroll
    for (int rr = 0; rr < 4; ++rr) {
      int row = 4 * q + rr;
      float v = acc2[ct][rr] + b2v;
      float zv = z[(zrowbase + row) * 64 + 16 * ct + lm];
      h2[(size_t)(rows0 + 16 * w + row) * 64 + 16 * ct + lm] = v;
      sv += v; sq += v * v; szh += zv * v; sz += zv; szq += zv * zv;
    }
    sv += __shfl_xor(sv, 16);  sv += __shfl_xor(sv, 32);
    sq += __shfl_xor(sq, 16);  sq += __shfl_xor(sq, 32);
    szh += __shfl_xor(szh, 16); szh += __shfl_xor(szh, 32);
    sz += __shfl_xor(sz, 16);  sz += __shfl_xor(sz, 32);
    szq += __shfl_xor(szq, 16); szq += __shfl_xor(szq, 32);
    if (l < 16) {
      float* rp = &red[w][(16 * ct + lm) * 5];
      rp[0] = sv; rp[1] = sq; rp[2] = szh; rp[3] = sz; rp[4] = szq;
    }
  }
  __syncthreads();
  // FIX (round 4 bug): block has 256 threads but 320 partial entries; the
  // old `if (t < 320)` left entries 256..319 unwritten (poisoned ws).
  for (int s = t; s < 320; s += 256) {
    float v = red[0][s] + red[1][s] + red[2][s] + red[3][s];
    cpart[(size_t)blockIdx.x * 320 + s] = v;
  }
}

// ---------------- reduce cpart -> colh2 ----------------
__global__ __launch_bounds__(256)
void k_cred(const float* __restrict__ cpart, float* __restrict__ colh2) {
  int idx = blockIdx.x * 256 + threadIdx.x;      // 2560 outputs
  if (idx >= 2560) return;
  int br = idx / 1280, rem = idx % 1280;
  int b = rem / 320, cs = rem % 320;
  const float* src = cpart + (size_t)br * 327680 + (size_t)b * 256 * 320 + cs;
  float s = 0.f;
  for (int rb = 0; rb < 256; ++rb) s += src[(size_t)rb * 320];
  colh2[idx] = s;
}

// ---------------- final stats: gn2 (exact) + gn3 (analytic) ----------------
__global__ __launch_bounds__(256)
void k_fstats(const float* __restrict__ colh2,
              const float* __restrict__ bg2w, const float* __restrict__ bg2b,
              const float* __restrict__ fg2w, const float* __restrict__ fg2b,
              float* __restrict__ alpha, float* __restrict__ beta,
              float* __restrict__ gn3) {
  __shared__ float m2r2[32][2];
  __shared__ float ab[2][4][64][2];
  int t = threadIdx.x;
  const float invR = 1.0f / 16384.0f;
  if (t < 32) {
    int br = t >> 4, b = (t >> 2) & 3, g = t & 3;
    float se = 0.f, sq = 0.f;
    for (int ci = 0; ci < 16; ++ci) {
      const float* ch = colh2 + (size_t)((br * 4 + b) * 64 + g * 16 + ci) * 5;
      se += ch[0]; sq += ch[1];
    }
    float mean = se * invR * 0.0625f;
    float Eq = sq * invR * 0.0625f;
    m2r2[t][0] = mean;
    m2r2[t][1] = rsqrtf(Eq - mean * mean + 1e-5f);
  }
  __syncthreads();
  #pragma unroll
  for (int rep = 0; rep < 2; ++rep) {
    int idx = t + rep * 256;
    int br = idx >> 8, b = (idx >> 6) & 3, c = idx & 63, g = c >> 4;
    const float* g2w = br ? fg2w : bg2w;
    const float* g2b = br ? fg2b : bg2b;
    float m2 = m2r2[(br * 4 + b) * 4 + g][0];
    float r2 = m2r2[(br * 4 + b) * 4 + g][1];
    float a = r2 * g2w[c];
    float bt = g2b[c] - m2 * a;
    ab[br][b][c][0] = a; ab[br][b][c][1] = bt;
    alpha[(br * 4 + b) * 64 + c] = a;
    beta[(br * 4 + b) * 64 + c] = bt;
  }
  __syncthreads();
  if (t < 32) {
    int br = t >> 4, b = (t >> 2) & 3, g = t & 3;
    float se = 0.f, sq = 0.f;
    for (int ci = 0; ci < 16; ++ci) {
      int c = g * 16 + ci;
      const float* ch = colh2 + (size_t)((br * 4 + b) * 64 + c) * 5;
      float Eh = ch[0] * invR, Eh2 = ch[1] * invR, Ezh = ch[2] * invR;
      float Ez = ch[3] * invR, Ez2 = ch[4] * invR;
      float a = ab[br][b][c][0], bt = ab[br][b][c][1];
      se += Ez + a * Eh + bt;
      sq += Ez2 + a * a * Eh2 + bt * bt + 2.f * a * Ezh + 2.f * bt * Ez + 2.f * a * bt * Eh;
    }
    float m3 = se * 0.0625f;
    float var = sq * 0.0625f - m3 * m3;
    gn3[t * 2] = m3;
    gn3[t * 2 + 1] = rsqrtf(var + 1e-5f);
  }
}

// ---------------- h3 + norm3 fused single pass ----------------
__global__ __launch_bounds__(256)
void k_h3final(const float* __restrict__ h2, const float* __restrict__ z,
               const float* __restrict__ alpha, const float* __restrict__ beta,
               const float* __restrict__ gn3, const float* __restrict__ g3w,
               const float* __restrict__ g3b, int br, float* __restrict__ out) {
  int t = threadIdx.x, bid = blockIdx.x;
  int b = bid >> 8, rc = bid & 255;
  int col = t & 63, rq = t >> 6;
  int g = col >> 4;
  float a = alpha[(br * 4 + b) * 64 + col];
  float bt = beta[(br * 4 + b) * 64 + col];
  float m3 = gn3[((br * 4 + b) * 4 + g) * 2];
  float r3 = gn3[((br * 4 + b) * 4 + g) * 2 + 1];
  float A2 = r3 * g3w[col];
  float B2 = g3b[col] - m3 * A2;
  size_t hbase = (size_t)b * 1048576 + (size_t)rc * 4096;
  size_t zbase = (size_t)(b * 2 + br) * 1048576 + (size_t)rc * 4096;
  for (int j = 0; j < 16; ++j) {
    size_t off = (size_t)(rq + 4 * j) * 64 + col;
    float h3 = z[zbase + off] + a * h2[hbase + off] + bt;
    out[zbase + off] = h3 * A2 + B2;
  }
}

extern "C" void kernel_launch(void* const* d_in, const int* in_sizes, int n_in,
                              void* d_out, int out_size, void* d_ws, size_t ws_size,
                              hipStream_t stream) {
  const float* z   = (const float*)d_in[0];
  const float* x   = (const float*)d_in[1];
  const float* fw1 = (const float*)d_in[2];
  const float* fw2 = (const float*)d_in[3];
  const float* P[20];
  for (int i = 0; i < 20; ++i) P[i] = (const float*)d_in[4 + i];
  // P[0..9] = b_{l1w,l1b,l2w,l2b,g1w,g1b,g2w,g2b,g3w,g3b}; P[10..19] = f_{...}

  float* ws = (float*)d_ws;
  float* xo    = ws + OFF_XO;
  float* S1    = ws + OFF_S1;
  float* cpart = ws + OFF_S1;      // alias (S1 dead after fft2)
  float* XF    = ws + OFF_XF;
  float* G     = ws + OFF_G;
  float* T     = ws + OFF_T;
  float* SSpart= ws + OFF_T;       // alias (T dead after inv2)
  float* wt    = ws + OFF_WT;
  float* TW1t  = ws + OFF_TW1;
  float* TW2t  = ws + OFF_TW2;
  float* CKt   = ws + OFF_CK;
  float* CMt   = ws + OFF_CM;
  float* h2f   = ws + OFF_H2;
  short* w1p   = (short*)(ws + OFF_WP);
  short* w2p   = w1p + 32768;
  float* CSpart= ws + OFF_CSP;
  float* SS    = ws + OFF_SS;
  float* CS    = ws + OFF_CS;
  float* cqp   = ws + OFF_CQP;
  float* cola  = ws + OFF_COLA;
  float* gn1   = ws + OFF_GN1;
  float* colh2 = ws + OFF_COLH2;
  float* alph  = ws + OFF_ALPHA;
  float* beta  = ws + OFF_BETA;
  float* gn3   = ws + OFF_GN3;
  float* out   = (float*)d_out;

  k_twfill<<<144, 256, 0, stream>>>(TW1t);
  k_wtrans<<<512, 256, 0, stream>>>(fw1, fw2, wt);
  k_wprep<<<256, 256, 0, stream>>>(P[0], P[10], P[2], P[12], w1p, w2p);
  k_fft1<<<512, 256, 0, stream>>>(x, z, TW1t, S1);
  k_fft2<<<128, 256, 0, stream>>>(S1, TW2t, XF);
  k_einsum<<<512, 256, 0, stream>>>(XF, wt, G);
  k_inv1<<<512, 256, 0, stream>>>(G, CKt, T);
  k_inv2<<<1024, 256, 0, stream>>>(T, CMt, xo);
  k_xostats<<<512, 256, 0, stream>>>(xo, SSpart, CSpart);
  k_ssred<<<65, 256, 0, stream>>>(SSpart, CSpart, SS, CS);
  k_colq<<<64, 256, 0, stream>>>(P[0], P[10], SS, CS, cqp, cola);
  k_gstats<<<1, 256, 0, stream>>>(cqp, cola, P[1], P[11], gn1);
  for (int br = 0; br < 2; ++br) {
    const float* const* q = P + br * 10;
    k_ffn<<<1024, 256, 0, stream>>>(xo, w1p, w2p, q[1], q[4], q[5], gn1 + br * 128,
                                    q[3], z, br, h2f + (size_t)br * 4194304,
                                    cpart + (size_t)br * 327680);
  }
  k_cred<<<10, 256, 0, stream>>>(cpart, colh2);
  k_fstats<<<1, 256, 0, stream>>>(colh2, P[6], P[7], P[16], P[17], alph, beta, gn3);
  for (int br = 0; br < 2; ++br) {
    const float* const* q = P + br * 10;
    k_h3final<<<1024, 256, 0, stream>>>(h2f + (size_t)br * 4194304, z, alph, beta, gn3,
                                        q[8], q[9], br, out);
  }
}

// Round 9
// 312.974 us; speedup vs baseline: 2.3204x; 1.0261x over previous
//
#include <hip/hip_runtime.h>
#include <math.h>

#define TWO_PI 6.28318530717958647692f

// ws float offsets
#define OFF_XO    0u
#define OFF_S1    4194304u   // aliased: cpart (2048 x 320) after fft2 consumed
#define OFF_XF    5242880u
#define OFF_G     5505024u
#define OFF_T     5767168u   // aliased: SSpart (512 x 4096) after inv2 consumed
#define OFF_WT    7864320u
#define OFF_TW1   12058624u
#define OFF_TW2   12062720u
#define OFF_CK    12079104u
#define OFF_CM    12087296u
#define OFF_WP    20484096u  // w1p/w2p packed bf16 (65536 shorts = 32768 floats)
#define OFF_CSP   20516864u  // CSpart 512 x 64
#define OFF_SS    20549632u  // 4 x 4096
#define OFF_CS    20566016u  // 4 x 64
#define OFF_CQP   20566272u  // colqpart 2 x 4 x 8 x 256
#define OFF_COLA  20582656u  // 2 x 4 x 256
#define OFF_GN1   20584704u  // 256
#define OFF_COLH2 20584960u  // 2 x 4 x 64 x 5
#define OFF_ALPHA 20587520u
#define OFF_BETA  20588032u
#define OFF_GN3   20588544u

typedef short bfrag __attribute__((ext_vector_type(8)));
typedef float f32x4 __attribute__((ext_vector_type(4)));

struct Params20 { const float* q[20]; };

__device__ __forceinline__ short f2bs(float f) {
  union { float f; unsigned u; } v; v.f = f;
  unsigned r = (v.u + 0x7fffu + ((v.u >> 16) & 1u)) >> 16;
  return (short)r;
}

// ---------------- merged setup: twiddle LUTs + wt transpose + FFN weight pack ----------------
__global__ __launch_bounds__(256)
void k_setup(float* __restrict__ lut, const float* __restrict__ fw1,
             const float* __restrict__ fw2, float* __restrict__ wt,
             const float* __restrict__ bW1, const float* __restrict__ fW1,
             const float* __restrict__ bW2, const float* __restrict__ fW2,
             short* __restrict__ w1p, short* __restrict__ w2p) {
  int bid = blockIdx.x, t = threadIdx.x;
  const float step = TWO_PI / 128.0f;
  if (bid < 144) {                        // twiddle LUT fill
    int idx = bid * 256 + t;
    if (idx < 4096) {                     // TW1t[v][2k+p]
      int v = idx >> 5, j = idx & 31, k = j >> 1, p = j & 1;
      float s, c; sincosf(step * (float)((k * v) & 127), &s, &c);
      lut[idx] = p ? -s : c;
    } else if (idx < 20480) {             // TW2t[2u+pp][2mi+p]
      int li = idx - 4096; int q = li >> 6, j3 = li & 63;
      int u = q >> 1, pp = q & 1, mi = j3 >> 1, p = j3 & 1;
      int m = mi < 16 ? mi : mi + 96;
      float s, c; sincosf(step * (float)((m * u) & 127), &s, &c);
      lut[idx] = pp == 0 ? (p == 0 ? c : -s) : (p == 0 ? s : c);
    } else if (idx < 28672) {             // CKt[2k+pp][2v+p]
      int li = idx - 20480; int j4 = li >> 8, r5 = li & 255;
      int k = j4 >> 1, pp = j4 & 1, v = r5 >> 1, p = r5 & 1;
      float ck = k ? 2.f : 1.f;
      float s, c; sincosf(step * (float)((k * v) & 127), &s, &c);
      lut[idx] = pp == 0 ? (p == 0 ? ck * c : ck * s) : (p == 0 ? -ck * s : ck * c);
    } else if (idx < 36864) {             // CMt[2mi+p][u]  (scale folded)
      int li = idx - 28672; int j5 = li >> 7, u = li & 127;
      int mi = j5 >> 1, p = j5 & 1; int m = mi < 16 ? mi : mi + 96;
      float s, c; sincosf(step * (float)((m * u) & 127), &s, &c);
      lut[idx] = (p == 0 ? c : -s) * (1.0f / 16384.0f);
    }
  } else if (bid < 656) {                 // wt[mi][k][i][o][2]
    int b2 = bid - 144;
    int mi = b2 >> 4, ic = b2 & 15;
    int i = ic * 4 + (t >> 6), o = t & 63;
    int xs = mi & 15;
    const float* src = (mi < 16 ? fw1 : fw2) + (size_t)(((i * 64 + o) * 16 + xs) * 16) * 2;
    float4 r[8];
    #pragma unroll
    for (int j = 0; j < 8; ++j) r[j] = ((const float4*)src)[j];
    float2* dst = (float2*)wt;
    #pragma unroll
    for (int j = 0; j < 8; ++j) {
      int k0 = 2 * j;
      dst[((size_t)(mi * 16 + k0) * 64 + i) * 64 + o]     = make_float2(r[j].x, r[j].y);
      dst[((size_t)(mi * 16 + k0 + 1) * 64 + i) * 64 + o] = make_float2(r[j].z, r[j].w);
    }
  } else {                                // FFN weight pack
    int idx = (bid - 656) * 256 + t;      // 65536 total
    if (idx < 32768) {                    // w1p[br][rt16][ks2][l64][j8]
      int br = idx >> 14, rem = idx & 16383;
      int rt = rem >> 10, ks = (rem >> 9) & 1;
      int l = (rem >> 3) & 63, j = rem & 7;
      const float* W = br ? fW1 : bW1;
      int kk = 32 * ks + (l >> 4) * 8 + j;
      int n = 16 * rt + (l & 15);
      w1p[idx] = f2bs(W[kk * 256 + n]);
    } else {                              // w2p[br][ct4][ks8][l64][j8]
      int i2 = idx - 32768;
      int br = i2 >> 14, rem = i2 & 16383;
      int ct = rem >> 12, ks = (rem >> 9) & 7;
      int l = (rem >> 3) & 63, j = rem & 7;
      const float* W = br ? fW2 : bW2;
      int kk = 32 * ks + (l >> 4) * 8 + j;
      int n = 16 * ct + (l & 15);
      w2p[i2] = f2bs(W[kk * 64 + n]);
    }
  }
}

// ---------------- fft1 ----------------
__global__ __launch_bounds__(256)
void k_fft1(const float* __restrict__ x, const float* __restrict__ z,
            const float* __restrict__ TW1t, float* __restrict__ S1) {
  __shared__ float diff[128 * 64];
  int t = threadIdx.x, bid = blockIdx.x;
  int b = bid >> 7, u = bid & 127;
  size_t bx = ((size_t)b * 16384 + (size_t)u * 128) * 64;
  size_t bz = ((size_t)b * 32768 + (size_t)u * 128) * 64;
  #pragma unroll
  for (int j = 0; j < 32; ++j) { int idx = t + 256 * j; diff[idx] = x[bx + idx] - z[bz + idx]; }
  __syncthreads();
  int kk = t >> 4, i0 = (t & 15) * 4;
  float r0[4] = {}, r1[4] = {};
  #pragma unroll 4
  for (int v = 0; v < 128; ++v) {
    float2 tw = *(const float2*)&TW1t[v * 32 + kk * 2];
    float4 d = *(const float4*)&diff[v * 64 + i0];
    float dv[4] = {d.x, d.y, d.z, d.w};
    #pragma unroll
    for (int q = 0; q < 4; ++q) { r0[q] += tw.x * dv[q]; r1[q] += tw.y * dv[q]; }
  }
  size_t o0 = ((size_t)b * 256 + 2 * u) * 1024 + kk * 64 + i0;
  *(float4*)&S1[o0]        = make_float4(r0[0], r0[1], r0[2], r0[3]);
  *(float4*)&S1[o0 + 1024] = make_float4(r1[0], r1[1], r1[2], r1[3]);
}

// ---------------- fft2 (512 blocks: b x rquarter x colchunk32) ----------------
__global__ __launch_bounds__(256)
void k_fft2(const float* __restrict__ S1, const float* __restrict__ TW2t,
            float* __restrict__ XF) {
  __shared__ float Bs[256 * 32];
  __shared__ float TWs[256 * 16];
  int t = threadIdx.x, bid = blockIdx.x;
  int b = bid >> 7, rq = (bid >> 5) & 3, ch = bid & 31;
  size_t sbase = (size_t)b * 262144 + ch * 32;
  #pragma unroll
  for (int j = 0; j < 32; ++j) {
    int idx = t + 256 * j; int q = idx >> 5, c = idx & 31;
    Bs[idx] = S1[sbase + (size_t)q * 1024 + c];
  }
  #pragma unroll
  for (int j = 0; j < 16; ++j) {
    int idx = t + 256 * j; int q = idx >> 4, rr = idx & 15;
    TWs[idx] = TW2t[q * 64 + rq * 16 + rr];
  }
  __syncthreads();
  int rr = t >> 4, c0 = (t & 15) * 2;
  float a0 = 0.f, a1 = 0.f;
  #pragma unroll 8
  for (int q = 0; q < 256; ++q) {
    float a = TWs[q * 16 + rr];
    float2 bb = *(const float2*)&Bs[q * 32 + c0];
    a0 += a * bb.x; a1 += a * bb.y;
  }
  int r = rq * 16 + rr;
  *(float2*)&XF[(size_t)b * 65536 + (size_t)r * 1024 + ch * 32 + c0] = make_float2(a0, a1);
}

// ---------------- einsum ----------------
__global__ __launch_bounds__(256)
void k_einsum(const float* __restrict__ XF, const float* __restrict__ wt,
              float* __restrict__ G) {
  __shared__ float xin[4][2][64];
  int t = threadIdx.x, bid = blockIdx.x;
  int mi = bid >> 4, k = bid & 15;
  #pragma unroll
  for (int rep = 0; rep < 2; ++rep) {
    int f = rep * 256 + t; int bb = f >> 7, rem = f & 127, p = rem >> 6, i = rem & 63;
    xin[bb][p][i] = XF[(size_t)bb * 65536 + (size_t)(2 * mi + p) * 1024 + k * 64 + i];
  }
  __syncthreads();
  int b = t >> 6, o = t & 63;
  float gr = 0.f, gi = 0.f;
  const float2* w2 = (const float2*)wt + (size_t)(mi * 16 + k) * 4096 + o;
  #pragma unroll 8
  for (int i = 0; i < 64; ++i) {
    float2 w = w2[(size_t)i * 64];
    float xr = xin[b][0][i], xi = xin[b][1][i];
    gr += xr * w.x - xi * w.y;
    gi += xr * w.y + xi * w.x;
  }
  size_t gb = ((size_t)(b * 32 + mi) * 32 + 2 * k) * 64 + o;
  G[gb] = gr; G[gb + 64] = gi;
}

// ---------------- inv1 ----------------
__global__ __launch_bounds__(256)
void k_inv1(const float* __restrict__ G, const float* __restrict__ CKt,
            float* __restrict__ T) {
  __shared__ float GG[32 * 64];
  int t = threadIdx.x, bid = blockIdx.x;
  int b = bid >> 7, mi = (bid >> 2) & 31, vq = bid & 3;
  size_t gbase = (size_t)(b * 32 + mi) * 2048;
  #pragma unroll
  for (int j = 0; j < 8; ++j) GG[t + 256 * j] = G[gbase + t + 256 * j];
  __syncthreads();
  int r0 = (t >> 4) * 4, o0 = (t & 15) * 4;
  float acc[4][4] = {};
  #pragma unroll 4
  for (int j4 = 0; j4 < 32; ++j4) {
    float4 a = *(const float4*)&CKt[j4 * 256 + vq * 64 + r0];
    float4 bb = *(const float4*)&GG[j4 * 64 + o0];
    float av[4] = {a.x, a.y, a.z, a.w}, bv[4] = {bb.x, bb.y, bb.z, bb.w};
    #pragma unroll
    for (int i = 0; i < 4; ++i)
      #pragma unroll
      for (int j = 0; j < 4; ++j) acc[i][j] += av[i] * bv[j];
  }
  #pragma unroll
  for (int ii = 0; ii < 4; ++ii) {
    int r = vq * 64 + r0 + ii; int v = r >> 1, p = r & 1;
    *(float4*)&T[((size_t)(b * 128 + v) * 64 + 2 * mi + p) * 64 + o0] =
        make_float4(acc[ii][0], acc[ii][1], acc[ii][2], acc[ii][3]);
  }
}

// ---------------- inv2 ----------------
__global__ __launch_bounds__(256)
void k_inv2(const float* __restrict__ T, const float* __restrict__ CMt,
            float* __restrict__ xo) {
  __shared__ float Ts[64 * 64];
  int t = threadIdx.x, bid = blockIdx.x;
  int b = bid >> 8, v = (bid >> 1) & 127, uh = bid & 1;
  size_t tb = (size_t)(b * 128 + v) * 4096;
  #pragma unroll
  for (int j = 0; j < 16; ++j) Ts[t + 256 * j] = T[tb + t + 256 * j];
  __syncthreads();
  int u0 = uh * 64 + (t >> 4) * 4, o0 = (t & 15) * 4;
  float acc[4][4] = {};
  #pragma unroll 4
  for (int j5 = 0; j5 < 64; ++j5) {
    float4 a = *(const float4*)&CMt[j5 * 128 + u0];
    float4 bb = *(const float4*)&Ts[j5 * 64 + o0];
    float av[4] = {a.x, a.y, a.z, a.w}, bv[4] = {bb.x, bb.y, bb.z, bb.w};
    #pragma unroll
    for (int i = 0; i < 4; ++i)
      #pragma unroll
      for (int j = 0; j < 4; ++j) acc[i][j] += av[i] * bv[j];
  }
  #pragma unroll
  for (int ii = 0; ii < 4; ++ii)
    *(float4*)&xo[(size_t)b * 1048576 + (size_t)(u0 + ii) * 8192 + v * 64 + o0] =
        make_float4(acc[ii][0], acc[ii][1], acc[ii][2], acc[ii][3]);
}

// ---------------- xo stats partials ----------------
__global__ __launch_bounds__(256)
void k_xostats(const float* __restrict__ xo, float* __restrict__ SSpart,
               float* __restrict__ CSpart) {
  __shared__ float Xs[128 * 64];
  int t = threadIdx.x, bid = blockIdx.x;
  size_t base = (size_t)bid * 8192;
  #pragma unroll
  for (int j = 0; j < 32; ++j) Xs[t + 256 * j] = xo[base + t + 256 * j];
  __syncthreads();
  int c1 = (t >> 4) * 4, c2 = (t & 15) * 4;
  float acc[4][4] = {};
  #pragma unroll 2
  for (int r = 0; r < 128; ++r) {
    float4 a = *(const float4*)&Xs[r * 64 + c1];
    float4 bb = *(const float4*)&Xs[r * 64 + c2];
    float av[4] = {a.x, a.y, a.z, a.w}, bv[4] = {bb.x, bb.y, bb.z, bb.w};
    #pragma unroll
    for (int i = 0; i < 4; ++i)
      #pragma unroll
      for (int j = 0; j < 4; ++j) acc[i][j] += av[i] * bv[j];
  }
  float* ssb = SSpart + (size_t)bid * 4096;
  #pragma unroll
  for (int i = 0; i < 4; ++i)
    #pragma unroll
    for (int j = 0; j < 4; ++j) ssb[(c1 + i) * 64 + c2 + j] = acc[i][j];
  if (t < 64) {
    float s = 0.f;
    for (int r = 0; r < 128; ++r) s += Xs[r * 64 + t];
    CSpart[(size_t)bid * 64 + t] = s;
  }
}

// ---------------- reduce SSpart/CSpart ----------------
__global__ __launch_bounds__(256)
void k_ssred(const float* __restrict__ SSpart, const float* __restrict__ CSpart,
             float* __restrict__ SS, float* __restrict__ CS) {
  int bid = blockIdx.x, t = threadIdx.x;
  if (bid < 64) {
    int idx = bid * 256 + t;
    int b = idx >> 12, e = idx & 4095;
    float s = 0.f;
    for (int rc = 0; rc < 128; ++rc) s += SSpart[(size_t)(b * 128 + rc) * 4096 + e];
    SS[idx] = s;
  } else {
    int b = t >> 6, c = t & 63;
    float s = 0.f;
    for (int rc = 0; rc < 128; ++rc) s += CSpart[(size_t)(b * 128 + rc) * 64 + c];
    CS[t] = s;
  }
}

// ---------------- per-col quadratic form partials ----------------
__global__ __launch_bounds__(256)
void k_colq(const float* __restrict__ bW1, const float* __restrict__ fW1,
            const float* __restrict__ SS, const float* __restrict__ CS,
            float* __restrict__ colqpart, float* __restrict__ cola) {
  int bid = blockIdx.x, t = threadIdx.x;
  int br = bid >> 5, b = (bid >> 3) & 3, jc = bid & 7;
  const float* W1 = br ? fW1 : bW1;
  float w[64];
  #pragma unroll
  for (int l = 0; l < 64; ++l) w[l] = W1[l * 256 + t];
  const float* ssb = SS + b * 4096;
  float q = 0.f;
  for (int jj = 0; jj < 8; ++jj) {
    int j = jc * 8 + jj;
    float sj = 0.f;
    #pragma unroll
    for (int l = 0; l < 64; ++l) sj += ssb[j * 64 + l] * w[l];
    q += W1[j * 256 + t] * sj;
  }
  colqpart[(size_t)bid * 256 + t] = q;
  if (jc == 0) {
    float a = 0.f;
    #pragma unroll
    for (int l = 0; l < 64; ++l) a += CS[b * 64 + l] * w[l];
    cola[(br * 4 + b) * 256 + t] = a;
  }
}

// ---------------- gn1 group stats (analytic) ----------------
__global__ __launch_bounds__(256)
void k_gstats(const float* __restrict__ colqpart, const float* __restrict__ cola,
              const float* __restrict__ bb1, const float* __restrict__ fb1,
              float* __restrict__ gn1) {
  int t = threadIdx.x; if (t >= 128) return;
  int br = t >> 6, bg = t & 63, b = bg >> 4, g = bg & 15;
  const float* b1 = br ? fb1 : bb1;
  const float invR = 1.0f / 16384.0f;
  float se = 0.f, sq = 0.f;
  for (int ci = 0; ci < 16; ++ci) {
    int c = g * 16 + ci;
    float A = cola[(br * 4 + b) * 256 + c];
    float Q = 0.f;
    #pragma unroll
    for (int jc = 0; jc < 8; ++jc)
      Q += colqpart[(size_t)((br * 4 + b) * 8 + jc) * 256 + c];
    float bc = b1[c];
    se += A * invR + bc;
    sq += (Q + 2.f * bc * A) * invR + bc * bc;
  }
  float mean = se * 0.0625f;
  float var = sq * 0.0625f - mean * mean;
  gn1[((br * 4 + b) * 16 + g) * 2] = mean;
  gn1[((br * 4 + b) * 16 + g) * 2 + 1] = rsqrtf(var + 1e-5f);
}

// ---------------- fused MFMA FFN, both branches in one grid ----------------
// PASS 1: accumulate col stats only (no h2 write).
// PASS 2: recompute h2 bit-identically, fuse h3 = z + a*h2 + bt and gn3 -> out.
template<int PASS>
__global__ __launch_bounds__(256)
void k_ffn(const float* __restrict__ xo, const short* __restrict__ w1p,
           const short* __restrict__ w2p, Params20 ps,
           const float* __restrict__ gn1, const float* __restrict__ z,
           float* __restrict__ cpart,
           const float* __restrict__ alpha, const float* __restrict__ beta,
           const float* __restrict__ gn3, float* __restrict__ out) {
  __shared__ short hact[4][16][264];     // per wave: 16 rows x (256+8 pad) bf16
  __shared__ float red[4][320];
  int t = threadIdx.x, bid = blockIdx.x;
  int w = t >> 6, l = t & 63, q = l >> 4, lm = l & 15;
  int br = bid >> 10;
  int rows0 = (bid & 1023) * 64;
  int b = rows0 >> 14;
  const float* const* P = ps.q + br * 10;
  const float* b1  = P[1];
  const float* g1w = P[4];
  const float* g1b = P[5];
  const float* b2  = P[3];
  const float* gn1b = gn1 + br * 128;

  // B-frags for GEMM1: xo rows (this wave's stripe), k = q*8+j (+32*ks)
  const float* xp = xo + (size_t)(rows0 + 16 * w + lm) * 64 + q * 8;
  bfrag bx0, bx1;
  {
    float4 a0 = *(const float4*)(xp);
    float4 a1 = *(const float4*)(xp + 4);
    float4 a2 = *(const float4*)(xp + 32);
    float4 a3 = *(const float4*)(xp + 36);
    float v0[8] = {a0.x, a0.y, a0.z, a0.w, a1.x, a1.y, a1.z, a1.w};
    float v1[8] = {a2.x, a2.y, a2.z, a2.w, a3.x, a3.y, a3.z, a3.w};
    #pragma unroll
    for (int j = 0; j < 8; ++j) { bx0[j] = f2bs(v0[j]); bx1[j] = f2bs(v1[j]); }
  }
  const bfrag* w1f = (const bfrag*)(w1p + (size_t)br * 16384);
  const bfrag* w2f = (const bfrag*)(w2p + (size_t)br * 16384);

  // GEMM1 + fused GN1/ReLU epilogue
  #pragma unroll 4
  for (int rt = 0; rt < 16; ++rt) {
    f32x4 c = {0.f, 0.f, 0.f, 0.f};
    c = __builtin_amdgcn_mfma_f32_16x16x32_bf16(w1f[(rt * 2 + 0) * 64 + l], bx0, c, 0, 0, 0);
    c = __builtin_amdgcn_mfma_f32_16x16x32_bf16(w1f[(rt * 2 + 1) * 64 + l], bx1, c, 0, 0, 0);
    int c1b = 16 * rt + 4 * q;           // group g == rt
    float4 l1 = *(const float4*)&b1[c1b];
    float4 gw = *(const float4*)&g1w[c1b];
    float4 gb = *(const float4*)&g1b[c1b];
    float gm = gn1b[(b * 16 + rt) * 2];
    float gr = gn1b[(b * 16 + rt) * 2 + 1];
    hact[w][lm][c1b + 0] = f2bs(fmaxf((c[0] + l1.x - gm) * gr * gw.x + gb.x, 0.f));
    hact[w][lm][c1b + 1] = f2bs(fmaxf((c[1] + l1.y - gm) * gr * gw.y + gb.y, 0.f));
    hact[w][lm][c1b + 2] = f2bs(fmaxf((c[2] + l1.z - gm) * gr * gw.z + gb.z, 0.f));
    hact[w][lm][c1b + 3] = f2bs(fmaxf((c[3] + l1.w - gm) * gr * gw.w + gb.w, 0.f));
  }

  // GEMM2 (same-wave LDS only -> no barrier needed before reads)
  f32x4 acc2[4];
  #pragma unroll
  for (int ct = 0; ct < 4; ++ct) acc2[ct] = (f32x4){0.f, 0.f, 0.f, 0.f};
  #pragma unroll
  for (int ks = 0; ks < 8; ++ks) {
    bfrag af = *(const bfrag*)&hact[w][lm][32 * ks + 8 * q];
    #pragma unroll
    for (int ct = 0; ct < 4; ++ct)
      acc2[ct] = __builtin_amdgcn_mfma_f32_16x16x32_bf16(af, w2f[(ct * 8 + ks) * 64 + l],
                                                         acc2[ct], 0, 0, 0);
  }

  size_t zrowbase = (size_t)(b * 2 + br) * 16384 + (size_t)(rows0 & 16383) + 16 * w;
  if (PASS == 1) {
    // stats only: (h2, h2^2, z*h2, z, z^2) per column
    #pragma unroll
    for (int ct = 0; ct < 4; ++ct) {
      float b2v = b2[16 * ct + lm];
      float sv = 0.f, sq = 0.f, szh = 0.f, sz = 0.f, szq = 0.f;
      #pragma unroll
      for (int rr = 0; rr < 4; ++rr) {
        int row = 4 * q + rr;
        float v = acc2[ct][rr] + b2v;
        float zv = z[(zrowbase + row) * 64 + 16 * ct + lm];
        sv += v; sq += v * v; szh += zv * v; sz += zv; szq += zv * zv;
      }
      sv += __shfl_xor(sv, 16);  sv += __shfl_xor(sv, 32);
      sq += __shfl_xor(sq, 16);  sq += __shfl_xor(sq, 32);
      szh += __shfl_xor(szh, 16); szh += __shfl_xor(szh, 32);
      sz += __shfl_xor(sz, 16);  sz += __shfl_xor(sz, 32);
      szq += __shfl_xor(szq, 16); szq += __shfl_xor(szq, 32);
      if (l < 16) {
        float* rp = &red[w][(16 * ct + lm) * 5];
        rp[0] = sv; rp[1] = sq; rp[2] = szh; rp[3] = sz; rp[4] = szq;
      }
    }
    __syncthreads();
    for (int s = t; s < 320; s += 256) {
      float v = red[0][s] + red[1][s] + red[2][s] + red[3][s];
      cpart[(size_t)bid * 320 + s] = v;
    }
  } else {
    // h3 + gn3 epilogue -> out
    const float* g3w = P[8];
    const float* g3b = P[9];
    int bb4 = br * 4 + b;
    #pragma unroll
    for (int ct = 0; ct < 4; ++ct) {
      int col = 16 * ct + lm;
      float b2v = b2[col];
      float a = alpha[bb4 * 64 + col];
      float bt = beta[bb4 * 64 + col];
      int g = col >> 4;
      float m3 = gn3[(bb4 * 4 + g) * 2];
      float r3 = gn3[(bb4 * 4 + g) * 2 + 1];
      float A2 = r3 * g3w[col];
      float B2 = g3b[col] - m3 * A2;
      #pragma unroll
      for (int rr = 0; rr < 4; ++rr) {
        int row = 4 * q + rr;
        float v = acc2[ct][rr] + b2v;
        size_t zi = (zrowbase + row) * 64 + col;
        float h3 = z[zi] + a * v + bt;
        out[zi] = h3 * A2 + B2;
      }
    }
  }
}

// ---------------- reduce cpart -> colh2 ----------------
__global__ __launch_bounds__(256)
void k_cred(const float* __restrict__ cpart, float* __restrict__ colh2) {
  int idx = blockIdx.x * 256 + threadIdx.x;      // 2560 outputs
  if (idx >= 2560) return;
  int br = idx / 1280, rem = idx % 1280;
  int b = rem / 320, cs = rem % 320;
  const float* src = cpart + (size_t)(br * 1024 + b * 256) * 320 + cs;
  float s = 0.f;
  for (int rb = 0; rb < 256; ++rb) s += src[(size_t)rb * 320];
  colh2[idx] = s;
}

// ---------------- final stats: gn2 (exact) + gn3 (analytic) ----------------
__global__ __launch_bounds__(256)
void k_fstats(const float* __restrict__ colh2,
              const float* __restrict__ bg2w, const float* __restrict__ bg2b,
              const float* __restrict__ fg2w, const float* __restrict__ fg2b,
              float* __restrict__ alpha, float* __restrict__ beta,
              float* __restrict__ gn3) {
  __shared__ float m2r2[32][2];
  __shared__ float ab[2][4][64][2];
  int t = threadIdx.x;
  const float invR = 1.0f / 16384.0f;
  if (t < 32) {
    int br = t >> 4, b = (t >> 2) & 3, g = t & 3;
    float se = 0.f, sq = 0.f;
    for (int ci = 0; ci < 16; ++ci) {
      const float* ch = colh2 + (size_t)((br * 4 + b) * 64 + g * 16 + ci) * 5;
      se += ch[0]; sq += ch[1];
    }
    float mean = se * invR * 0.0625f;
    float Eq = sq * invR * 0.0625f;
    m2r2[t][0] = mean;
    m2r2[t][1] = rsqrtf(Eq - mean * mean + 1e-5f);
  }
  __syncthreads();
  #pragma unroll
  for (int rep = 0; rep < 2; ++rep) {
    int idx = t + rep * 256;
    int br = idx >> 8, b = (idx >> 6) & 3, c = idx & 63, g = c >> 4;
    const float* g2w = br ? fg2w : bg2w;
    const float* g2b = br ? fg2b : bg2b;
    float m2 = m2r2[(br * 4 + b) * 4 + g][0];
    float r2 = m2r2[(br * 4 + b) * 4 + g][1];
    float a = r2 * g2w[c];
    float bt = g2b[c] - m2 * a;
    ab[br][b][c][0] = a; ab[br][b][c][1] = bt;
    alpha[(br * 4 + b) * 64 + c] = a;
    beta[(br * 4 + b) * 64 + c] = bt;
  }
  __syncthreads();
  if (t < 32) {
    int br = t >> 4, b = (t >> 2) & 3, g = t & 3;
    float se = 0.f, sq = 0.f;
    for (int ci = 0; ci < 16; ++ci) {
      int c = g * 16 + ci;
      const float* ch = colh2 + (size_t)((br * 4 + b) * 64 + c) * 5;
      float Eh = ch[0] * invR, Eh2 = ch[1] * invR, Ezh = ch[2] * invR;
      float Ez = ch[3] * invR, Ez2 = ch[4] * invR;
      float a = ab[br][b][c][0], bt = ab[br][b][c][1];
      se += Ez + a * Eh + bt;
      sq += Ez2 + a * a * Eh2 + bt * bt + 2.f * a * Ezh + 2.f * bt * Ez + 2.f * a * bt * Eh;
    }
    float m3 = se * 0.0625f;
    float var = sq * 0.0625f - m3 * m3;
    gn3[t * 2] = m3;
    gn3[t * 2 + 1] = rsqrtf(var + 1e-5f);
  }
}

extern "C" void kernel_launch(void* const* d_in, const int* in_sizes, int n_in,
                              void* d_out, int out_size, void* d_ws, size_t ws_size,
                              hipStream_t stream) {
  const float* z   = (const float*)d_in[0];
  const float* x   = (const float*)d_in[1];
  const float* fw1 = (const float*)d_in[2];
  const float* fw2 = (const float*)d_in[3];
  Params20 ps;
  for (int i = 0; i < 20; ++i) ps.q[i] = (const float*)d_in[4 + i];
  // q[0..9] = b_{l1w,l1b,l2w,l2b,g1w,g1b,g2w,g2b,g3w,g3b}; q[10..19] = f_{...}

  float* ws = (float*)d_ws;
  float* xo    = ws + OFF_XO;
  float* S1    = ws + OFF_S1;
  float* cpart = ws + OFF_S1;      // alias (S1 dead after fft2)
  float* XF    = ws + OFF_XF;
  float* G     = ws + OFF_G;
  float* T     = ws + OFF_T;
  float* SSpart= ws + OFF_T;       // alias (T dead after inv2)
  float* wt    = ws + OFF_WT;
  float* TW1t  = ws + OFF_TW1;
  float* TW2t  = ws + OFF_TW2;
  float* CKt   = ws + OFF_CK;
  float* CMt   = ws + OFF_CM;
  short* w1p   = (short*)(ws + OFF_WP);
  short* w2p   = w1p + 32768;
  float* CSpart= ws + OFF_CSP;
  float* SS    = ws + OFF_SS;
  float* CS    = ws + OFF_CS;
  float* cqp   = ws + OFF_CQP;
  float* cola  = ws + OFF_COLA;
  float* gn1   = ws + OFF_GN1;
  float* colh2 = ws + OFF_COLH2;
  float* alph  = ws + OFF_ALPHA;
  float* beta  = ws + OFF_BETA;
  float* gn3   = ws + OFF_GN3;
  float* out   = (float*)d_out;

  k_setup<<<912, 256, 0, stream>>>(TW1t, fw1, fw2, wt,
                                   ps.q[0], ps.q[10], ps.q[2], ps.q[12], w1p, w2p);
  k_fft1<<<512, 256, 0, stream>>>(x, z, TW1t, S1);
  k_fft2<<<512, 256, 0, stream>>>(S1, TW2t, XF);
  k_einsum<<<512, 256, 0, stream>>>(XF, wt, G);
  k_inv1<<<512, 256, 0, stream>>>(G, CKt, T);
  k_inv2<<<1024, 256, 0, stream>>>(T, CMt, xo);
  k_xostats<<<512, 256, 0, stream>>>(xo, SSpart, CSpart);
  k_ssred<<<65, 256, 0, stream>>>(SSpart, CSpart, SS, CS);
  k_colq<<<64, 256, 0, stream>>>(ps.q[0], ps.q[10], SS, CS, cqp, cola);
  k_gstats<<<1, 256, 0, stream>>>(cqp, cola, ps.q[1], ps.q[11], gn1);
  k_ffn<1><<<2048, 256, 0, stream>>>(xo, w1p, w2p, ps, gn1, z, cpart,
                                     nullptr, nullptr, nullptr, nullptr);
  k_cred<<<10, 256, 0, stream>>>(cpart, colh2);
  k_fstats<<<1, 256, 0, stream>>>(colh2, ps.q[6], ps.q[7], ps.q[16], ps.q[17],
                                  alph, beta, gn3);
  k_ffn<2><<<2048, 256, 0, stream>>>(xo, w1p, w2p, ps, gn1, z, cpart,
                                     alph, beta, gn3, out);
}